// Round 10
// baseline (154.128 us; speedup 1.0000x reference)
//
#include <hip/hip_runtime.h>
#include <hip/hip_fp16.h>

#define N_NODES 50000
#define N_EDGES 800000
#define D_FEAT  64
#define BSHIFT  6
#define NBKT    782               // ceil(50000/64)
#define NB      256               // coarse blocks (1 per CU)
#define CHUNK   3125              // 256*3125 = 800000 exactly
#define CAST_CHUNK 12500          // 3.2M/256
#define PSHIFT  20
#define SRC_MASK ((1 << PSHIFT) - 1)   // src < 50000 < 2^20

// ---------- workspace layout (ints) ----------
#define WS_FLAG    0
#define WS_TOT     64                         // per-bucket totals [NBKT]
#define WS_COFF    (WS_TOT + NBKT)            // bucket base offsets [NBKT+1]
#define WS_BH      (WS_COFF + NBKT + 1)       // per-(bucket,block) counts [NBKT*NB]
#define WS_OFFS    (WS_BH + NBKT * NB)        // per-node offsets [N_NODES+1]
#define WS_PAIR    (WS_OFFS + N_NODES + 1)    // packed (src|dstlow<<20) [N_EDGES]
#define WS_SSRC    (WS_PAIR + N_EDGES)        // dst-sorted src [N_EDGES]
#define WS_PACKED  (WS_SSRC + N_EDGES)        // __half2[N_NODES*D_FEAT]
#define WS_INTS    (WS_PACKED + N_NODES * D_FEAT)

__device__ inline int detect_idx_layout_local(const int* idx) {
    // indices < 50000: if stored as int64 LE, every odd 32-bit word is 0.
    int allzero = 1;
    #pragma unroll
    for (int i = 1; i < 129; i += 2) {
        if (idx[i] != 0) allzero = 0;
    }
    return allzero;
}

// K0: fused cast + per-block coarse hist. 256 blocks.
__global__ __launch_bounds__(256) void cast_hist(int* __restrict__ W,
                                                 const int* __restrict__ idx,
                                                 const float* __restrict__ xs,
                                                 const float* __restrict__ xp) {
    __shared__ int h[NBKT];
    for (int i = threadIdx.x; i < NBKT; i += 256) h[i] = 0;
    __syncthreads();

    const int flg = detect_idx_layout_local(idx);   // per-block, no global dep
    const int t = threadIdx.x;

    // cast slice
    __half2* packed = (__half2*)(W + WS_PACKED);
    const int cbase = blockIdx.x * CAST_CHUNK;
    for (int i = cbase + t; i < cbase + CAST_CHUNK; i += 256)
        packed[i] = __floats2half2_rn(xs[i], xp[i]);

    // hist slice
    const int base = blockIdx.x * CHUNK;
    for (int e = base + t; e < base + CHUNK; e += 256) {
        int dst = flg ? idx[2 * (N_EDGES + e)] : idx[N_EDGES + e];
        atomicAdd(&h[dst >> BSHIFT], 1);
    }
    __syncthreads();
    for (int i = t; i < NBKT; i += 256)
        W[WS_BH + i * NB + blockIdx.x] = h[i];
    if (blockIdx.x == 0 && t == 0) {
        W[WS_FLAG] = flg;
        W[WS_OFFS + N_NODES] = N_EDGES;
    }
}

// K1: per-bucket exclusive scan over NB block counts (coalesced) -> excl + totals
__global__ __launch_bounds__(256) void bucket_scan(int* __restrict__ W) {
    __shared__ int part[NB];
    int j = blockIdx.x;           // bucket
    int t = threadIdx.x;          // block index
    int c = W[WS_BH + j * NB + t];
    part[t] = c;
    __syncthreads();
    for (int off = 1; off < NB; off <<= 1) {
        int u = (t >= off) ? part[t - off] : 0;
        __syncthreads();
        part[t] += u;
        __syncthreads();
    }
    W[WS_BH + j * NB + t] = part[t] - c;   // exclusive within-bucket offset
    if (t == NB - 1) W[WS_TOT + j] = part[t];
}

// K2: single-block scan of bucket totals -> COFF
__global__ __launch_bounds__(1024) void base_scan(int* __restrict__ W) {
    __shared__ int part[1024];
    int t = threadIdx.x;
    int v = (t < NBKT) ? W[WS_TOT + t] : 0;
    part[t] = v;
    __syncthreads();
    for (int off = 1; off < 1024; off <<= 1) {
        int u = (t >= off) ? part[t - off] : 0;
        __syncthreads();
        part[t] += u;
        __syncthreads();
    }
    if (t < NBKT) W[WS_COFF + t] = part[t] - v;
    if (t == 0) W[WS_COFF + NBKT] = N_EDGES;
}

// K3: deterministic coarse scatter — LDS cursors, no global atomics
__global__ __launch_bounds__(256) void coarse_scatter(const int* __restrict__ idx,
                                                      int* __restrict__ W) {
    __shared__ int cur[NBKT];
    for (int i = threadIdx.x; i < NBKT; i += 256)
        cur[i] = W[WS_COFF + i] + W[WS_BH + i * NB + blockIdx.x];
    __syncthreads();
    const int flg = W[WS_FLAG];
    const int base = blockIdx.x * CHUNK;
    for (int e = base + threadIdx.x; e < base + CHUNK; e += 256) {
        int src, dst;
        if (flg) { src = idx[2 * e]; dst = idx[2 * (N_EDGES + e)]; }
        else     { src = idx[e];     dst = idx[N_EDGES + e]; }
        int pos = atomicAdd(&cur[dst >> BSHIFT], 1);
        W[WS_PAIR + pos] = src | ((dst & 63) << PSHIFT);
    }
}

// K4: per-bucket fine counting sort with per-wave privatized hist/cursors.
__global__ __launch_bounds__(256) void fine_sort(int* __restrict__ W) {
    __shared__ int h[4][64];
    int b = blockIdx.x;
    int t = threadIdx.x;
    int w = t >> 6;
    int lane = t & 63;
    int bbase = W[WS_COFF + b];
    int bend  = W[WS_COFF + b + 1];
    h[w][lane] = 0;
    __syncthreads();
    // pass 1: per-wave hist (wave w owns edges bbase + w*64 + lane, stride 256)
    for (int e = bbase + t; e < bend; e += 256)
        atomicAdd(&h[w][(unsigned)W[WS_PAIR + e] >> PSHIFT], 1);
    __syncthreads();
    if (t < 64) {
        int c0 = h[0][t], c1 = h[1][t], c2 = h[2][t], c3 = h[3][t];
        int tot = c0 + c1 + c2 + c3;
        int incl = tot;
        #pragma unroll
        for (int off = 1; off < 64; off <<= 1) {
            int u = __shfl_up(incl, off, 64);
            if (t >= off) incl += u;
        }
        int excl = incl - tot;
        int node = (b << BSHIFT) + t;
        if (node < N_NODES) W[WS_OFFS + node] = bbase + excl;
        // per-wave cursor bases
        h[0][t] = excl;
        h[1][t] = excl + c0;
        h[2][t] = excl + c0 + c1;
        h[3][t] = excl + c0 + c1 + c2;
    }
    __syncthreads();
    // pass 2: same per-wave edge set, private cursors
    for (int e = bbase + t; e < bend; e += 256) {
        int v = W[WS_PAIR + e];
        int p = atomicAdd(&h[w][(unsigned)v >> PSHIFT], 1);
        W[WS_SSRC + bbase + p] = v & SRC_MASK;
    }
}

// K5: one wave per node; lane = feature; fp16 interleaved gathers, fp32 accum.
// 16-deep main pipeline (covers avg degree), 4-deep tail, scalar remainder.
__global__ __launch_bounds__(256) void gather_reduce(const int* __restrict__ W,
                                                     float* __restrict__ out) {
    int wave = (int)((blockIdx.x * blockDim.x + threadIdx.x) >> 6);
    int lane = threadIdx.x & 63;
    if (wave >= N_NODES) return;
    int beg = __builtin_amdgcn_readfirstlane(W[WS_OFFS + wave]);
    int end = __builtin_amdgcn_readfirstlane(W[WS_OFFS + wave + 1]);
    const int* ssrc = W + WS_SSRC;
    const __half2* packed = (const __half2*)(W + WS_PACKED);

    float s0 = 0.f, s1 = 0.f, s2 = 0.f, s3 = 0.f;
    float s4 = 0.f, s5 = 0.f, s6 = 0.f, s7 = 0.f;
    float p0 = 1.f, p1 = 1.f, p2 = 1.f, p3 = 1.f;
    float p4 = 1.f, p5 = 1.f, p6 = 1.f, p7 = 1.f;
    int i = beg;
    for (; i + 15 < end; i += 16) {
        float2 f[16];
        #pragma unroll
        for (int k = 0; k < 16; ++k)
            f[k] = __half22float2(packed[ssrc[i + k] * D_FEAT + lane]);
        s0 += f[0].x + f[8].x;  s1 += f[1].x + f[9].x;
        s2 += f[2].x + f[10].x; s3 += f[3].x + f[11].x;
        s4 += f[4].x + f[12].x; s5 += f[5].x + f[13].x;
        s6 += f[6].x + f[14].x; s7 += f[7].x + f[15].x;
        p0 *= f[0].y * f[8].y;  p1 *= f[1].y * f[9].y;
        p2 *= f[2].y * f[10].y; p3 *= f[3].y * f[11].y;
        p4 *= f[4].y * f[12].y; p5 *= f[5].y * f[13].y;
        p6 *= f[6].y * f[14].y; p7 *= f[7].y * f[15].y;
    }
    for (; i + 3 < end; i += 4) {
        float2 f0 = __half22float2(packed[ssrc[i] * D_FEAT + lane]);
        float2 f1 = __half22float2(packed[ssrc[i + 1] * D_FEAT + lane]);
        float2 f2 = __half22float2(packed[ssrc[i + 2] * D_FEAT + lane]);
        float2 f3 = __half22float2(packed[ssrc[i + 3] * D_FEAT + lane]);
        s0 += f0.x; s1 += f1.x; s2 += f2.x; s3 += f3.x;
        p0 *= f0.y; p1 *= f1.y; p2 *= f2.y; p3 *= f3.y;
    }
    for (; i < end; ++i) {
        float2 f = __half22float2(packed[ssrc[i] * D_FEAT + lane]);
        s0 += f.x;
        p0 *= f.y;
    }
    float ssum = ((s0 + s1) + (s2 + s3)) + ((s4 + s5) + (s6 + s7));
    float pprd = ((p0 * p1) * (p2 * p3)) * ((p4 * p5) * (p6 * p7));
    out[(long)wave * D_FEAT + lane] = ssum;
    out[(long)N_NODES * D_FEAT + (long)wave * D_FEAT + lane] = pprd;
}

// ---------------- fallback (atomic) path, used only if ws is too small ----------------
__device__ inline void atomicMulF32(float* addr, float val) {
    unsigned int* ua = (unsigned int*)addr;
    unsigned int old = __hip_atomic_load(ua, __ATOMIC_RELAXED, __HIP_MEMORY_SCOPE_AGENT);
    while (true) {
        unsigned int assumed = old;
        unsigned int desired = __float_as_uint(__uint_as_float(assumed) * val);
        old = atomicCAS(ua, assumed, desired);
        if (old == assumed) break;
    }
}

__global__ void fb_init(float* __restrict__ out, int* __restrict__ flag,
                        const int* __restrict__ idx) {
    const int n4 = (N_NODES * D_FEAT) / 4;
    int tid = blockIdx.x * blockDim.x + threadIdx.x;
    int stride = gridDim.x * blockDim.x;
    float4* o = (float4*)out;
    const float4 z = make_float4(0.f, 0.f, 0.f, 0.f);
    const float4 one = make_float4(1.f, 1.f, 1.f, 1.f);
    for (int i = tid; i < n4; i += stride) { o[i] = z; o[n4 + i] = one; }
    if (blockIdx.x == 0 && threadIdx.x == 0) *flag = detect_idx_layout_local(idx);
}

__global__ void fb_scatter(const float* __restrict__ xs, const float* __restrict__ xp,
                           const int* __restrict__ idx, float* __restrict__ out,
                           const int* __restrict__ flag) {
    long tid = (long)blockIdx.x * blockDim.x + threadIdx.x;
    const long total = (long)N_EDGES * (D_FEAT / 4);
    if (tid >= total) return;
    int e = (int)(tid >> 4);
    int c = (int)(tid & 15);
    int src, dst;
    if (*flag) { src = idx[2 * e]; dst = idx[2 * (N_EDGES + e)]; }
    else       { src = idx[e];     dst = idx[N_EDGES + e]; }
    const float4 s = ((const float4*)(xs + (long)src * D_FEAT))[c];
    const float4 p = ((const float4*)(xp + (long)src * D_FEAT))[c];
    float* os = out + (long)dst * D_FEAT + c * 4;
    float* op = out + (long)N_NODES * D_FEAT + (long)dst * D_FEAT + c * 4;
    atomicAdd(os + 0, s.x); atomicAdd(os + 1, s.y);
    atomicAdd(os + 2, s.z); atomicAdd(os + 3, s.w);
    atomicMulF32(op + 0, p.x); atomicMulF32(op + 1, p.y);
    atomicMulF32(op + 2, p.z); atomicMulF32(op + 3, p.w);
}

extern "C" void kernel_launch(void* const* d_in, const int* in_sizes, int n_in,
                              void* d_out, int out_size, void* d_ws, size_t ws_size,
                              hipStream_t stream) {
    const float* x_sum  = (const float*)d_in[0];
    const float* x_prod = (const float*)d_in[1];
    const int*   eidx   = (const int*)d_in[2];
    float* out = (float*)d_out;
    int* W = (int*)d_ws;

    if (ws_size < (size_t)WS_INTS * sizeof(int)) {
        fb_init<<<1024, 256, 0, stream>>>(out, W, eidx);
        const long total = (long)N_EDGES * (D_FEAT / 4);
        int grid = (int)((total + 255) / 256);
        fb_scatter<<<grid, 256, 0, stream>>>(x_sum, x_prod, eidx, out, W);
        return;
    }

    cast_hist<<<NB, 256, 0, stream>>>(W, eidx, x_sum, x_prod);
    bucket_scan<<<NBKT, 256, 0, stream>>>(W);
    base_scan<<<1, 1024, 0, stream>>>(W);
    coarse_scatter<<<NB, 256, 0, stream>>>(eidx, W);
    fine_sort<<<NBKT, 256, 0, stream>>>(W);
    gather_reduce<<<(N_NODES + 3) / 4, 256, 0, stream>>>(W, out);
}